// Round 8
// baseline (672.002 us; speedup 1.0000x reference)
//
#include <hip/hip_runtime.h>
#include <hip/hip_cooperative_groups.h>
#include <stdint.h>

#pragma clang fp contract(off)

namespace cg = cooperative_groups;

#define N_ELEM   1048576
#define MAX_NMS  30000
#define MAX_DET  300
#define IOU_T    0.45f
#define CONF_T   0.25f
#define SOA_N    30720
#define KMIN     0xBE800000u
#define EQCAP    2048
#define RPW      16
#define GRID     512
#define NTHR     (GRID*256)

typedef uint32_t u32;
typedef unsigned long long u64;

// ctrl word indices
#define C_CB   0
#define C_KP   1
#define C_A    2
#define C_NUM  3
#define C_EQC  4

__device__ inline u32 monokey(float s){
  u32 b = __float_as_uint(s);
  return b ^ ((b & 0x80000000u) ? 0xFFFFFFFFu : 0x80000000u);
}
__device__ inline int binOf(u32 k){
  u32 d = (k - KMIN) >> 8;
  return d > 65535u ? 65535 : (int)d;
}
__device__ inline u64 shfl64(u64 v, int src){
  int lo = __shfl((int)(u32)(v & 0xFFFFFFFFull), src);
  int hi = __shfl((int)(u32)(v >> 32), src);
  return ((u64)(u32)hi << 32) | (u32)lo;
}

struct KParams {
  const float* pred;
  u32* keys; u32* hist; u32* binCursor; u32* ctrl; u32* chunkSum;
  u32* binBase; u32* eqKey; u32* eqIdx; u32* binnedKey; u32* binnedIdx;
  float* soa; u64* mask;
  int W, WBsh;
};

__device__ inline void writeSoA(const float* __restrict__ pred, float* __restrict__ soa,
                                u32 r, u32 i){
  const float* row = pred + (size_t)i*7;
  float x = row[0], y = row[1], w = row[2], hh = row[3];
  float obj = row[4], c0 = row[5], c1 = row[6];
  float p0 = c0*obj, p1 = c1*obj;
  float conf = fmaxf(p0, p1);
  float jf = (p0 >= p1) ? 0.0f : 1.0f;
  float bx1 = x - w*0.5f, by1 = y - hh*0.5f;
  float bx2 = x + w*0.5f, by2 = y + hh*0.5f;
  float off = jf * 4096.0f;
  float ox1 = bx1 + off, oy1 = by1 + off, ox2 = bx2 + off, oy2 = by2 + off;
  float area = (ox2 - ox1) * (oy2 - oy1);
  soa[r + 0*SOA_N] = ox1;  soa[r + 1*SOA_N] = oy1;
  soa[r + 2*SOA_N] = ox2;  soa[r + 3*SOA_N] = oy2;
  soa[r + 4*SOA_N] = area; soa[r + 5*SOA_N] = conf;
  soa[r + 6*SOA_N] = jf;
  soa[r + 7*SOA_N] = bx1;  soa[r + 8*SOA_N] = by1;
  soa[r + 9*SOA_N] = bx2;  soa[r +10*SOA_N] = by2;
}

// ---- everything except the walk, in one cooperative kernel ----
__global__ void __launch_bounds__(256, 2) kfused(KParams P){
  cg::grid_group grid = cg::this_grid();
  int tid = threadIdx.x, bid = blockIdx.x;
  int gtid = bid*256 + tid;
  int lane = tid & 63, wv = tid >> 6;

  __shared__ float stage[1792];
  __shared__ u32 csum[1024];
  __shared__ u32 s256[256];
  __shared__ u32 above[1024];
  __shared__ int selC;
  __shared__ u32 dl[64];

  // ---- P0: zero hist + binCursor + ctrl ----
  if (gtid < 65536){ P.hist[gtid] = 0; P.binCursor[gtid] = 0; }
  if (gtid < 64) P.ctrl[gtid] = 0;
  grid.sync();

  // ---- P1: keys + 64K-bin histogram (LDS-staged, 8 tiles/block) ----
  {
    const float4* pred4 = (const float4*)P.pred;
    for (int tile = 0; tile < 8; tile++){
      int tb = bid*8 + tile;
      const float4* src = pred4 + (size_t)tb*448;
      float4* l4 = (float4*)stage;
      __syncthreads();
      #pragma unroll
      for (int k = 0; k < 2; k++){
        int idx = k*256 + tid;
        if (idx < 448) l4[idx] = src[idx];
      }
      __syncthreads();
      float obj = stage[tid*7+4], c0 = stage[tid*7+5], c1 = stage[tid*7+6];
      float p0 = c0*obj, p1 = c1*obj;
      float conf = fmaxf(p0, p1);
      bool valid = (obj > CONF_T) && (conf > CONF_T);
      float score = valid ? conf : -1.0f;
      u32 mk = monokey(score);
      P.keys[tb*256 + tid] = mk;
      if (mk > KMIN) atomicAdd(&P.hist[binOf(mk)], 1u);
    }
  }
  grid.sync();

  // ---- P2: chunk sums (2 chunks/block, waves 0-1) ----
  if (wv < 2){
    int c = bid*2 + wv;
    u32 v = P.hist[c*64 + lane];
    #pragma unroll
    for (int off = 32; off > 0; off >>= 1) v += __shfl_down(v, off);
    if (lane == 0) P.chunkSum[c] = v;
  }
  grid.sync();

  // ---- P3: redundant per-block chunk suffix-scan; bid0 picks cutoff; binBase ----
  {
    for (int j = 0; j < 4; j++) csum[j*256 + tid] = P.chunkSum[j*256 + tid];
    __syncthreads();
    u32 o0 = csum[tid*4], o1 = csum[tid*4+1], o2 = csum[tid*4+2], o3 = csum[tid*4+3];
    u32 g = o0 + o1 + o2 + o3;
    s256[tid] = g; __syncthreads();
    for (int off = 1; off < 256; off <<= 1){
      u32 v = s256[tid];
      u32 add = (tid + off < 256) ? s256[tid + off] : 0u;
      __syncthreads();
      s256[tid] = v + add;
      __syncthreads();
    }
    u32 aboveG = s256[tid] - g;
    u32 grand = s256[0];
    above[tid*4+0] = aboveG + o1 + o2 + o3;
    above[tid*4+1] = aboveG + o2 + o3;
    above[tid*4+2] = aboveG + o3;
    above[tid*4+3] = aboveG;
    const u32 K = MAX_NMS;
    if (tid == 0) selC = 0;
    __syncthreads();
    #pragma unroll
    for (int j = 0; j < 4; j++){
      int c = tid*4 + j;
      u32 ab = above[c], cs = csum[c];
      if (grand >= K && ab < K && K <= ab + cs) selC = c;   // unique winner
    }
    __syncthreads();
    if (bid == 0){
      if (grand < K){
        if (tid == 0){
          P.ctrl[C_CB] = 0xFFFFFFFFu; P.ctrl[C_KP] = 0;
          P.ctrl[C_A] = grand; P.ctrl[C_NUM] = grand;
        }
      } else {
        if (tid < 64) dl[tid] = P.hist[selC*64 + tid];
        __syncthreads();
        if (tid == 0){
          u32 cum = above[selC];
          for (int b = 63; b >= 0; b--){
            u32 c = dl[b];
            if (cum + c >= K){
              P.ctrl[C_CB] = (u32)(selC*64 + b);
              P.ctrl[C_KP] = K - cum;
              P.ctrl[C_A]  = cum;
              P.ctrl[C_NUM] = K;
              break;
            }
            cum += c;
          }
        }
      }
    }
    __syncthreads();
    // binBase for this block's 2 chunks (waves 0-1)
    if (wv < 2){
      int c = bid*2 + wv;
      u32 v = P.hist[c*64 + lane];
      u32 suf = v;
      #pragma unroll
      for (int off = 1; off < 64; off <<= 1){
        u32 o = __shfl_down(suf, off);
        suf += (lane + off < 64) ? o : 0u;
      }
      P.binBase[c*64 + lane] = above[c] + suf - v;
    }
  }
  grid.sync();

  // ---- P4: scatter into per-bin slots; cutoff bin -> eq list ----
  {
    const uint4* keys4 = (const uint4*)P.keys;
    int cb = (int)P.ctrl[C_CB];
    for (int t4 = gtid; t4 < N_ELEM/4; t4 += NTHR){
      uint4 kv = keys4[t4];
      u32 kk[4] = {kv.x, kv.y, kv.z, kv.w};
      #pragma unroll
      for (int r = 0; r < 4; r++){
        u32 k = kk[r];
        if (k <= KMIN) continue;
        int b = binOf(k);
        u32 i = (u32)(t4*4 + r);
        if (b > cb){
          u32 pos = P.binBase[b] + atomicAdd(&P.binCursor[b], 1u);
          if (pos < MAX_NMS){ P.binnedKey[pos] = k; P.binnedIdx[pos] = i; }
        } else if (b == cb){
          u32 e = atomicAdd(&P.ctrl[C_EQC], 1u);
          if (e < EQCAP){ P.eqKey[e] = k; P.eqIdx[e] = i; }
        }
      }
    }
  }
  grid.sync();

  // ---- P5: exact rank + eq-tie resolve + gather to SoA ----
  {
    int p = gtid;
    u32 A = P.ctrl[C_A], Kp = P.ctrl[C_KP];
    if (Kp > 0){
      u32 n = P.ctrl[C_EQC]; if (n > EQCAP) n = EQCAP;
      if (p < (int)n){
        u32 k = P.eqKey[p], i = P.eqIdx[p];
        u32 r = 0;
        for (u32 m = 0; m < n; m++){
          u32 km = P.eqKey[m], im = P.eqIdx[m];
          r += (km > k) || (km == k && im < i);
        }
        if (r < Kp) writeSoA(P.pred, P.soa, A + r, i);
      }
    }
    if (p < (int)A){
      u32 k = P.binnedKey[p]; u32 i = P.binnedIdx[p];
      if (i >= N_ELEM) i = 0;
      int b = binOf(k);
      u32 st = P.binBase[b], cnt = P.hist[b];
      u32 r = st;
      for (u32 q = st; q < st + cnt; q++){
        u32 kq = P.binnedKey[q], iq = P.binnedIdx[q];
        if (kq > k || (kq == k && iq < i)) r++;
      }
      if (r < A) writeSoA(P.pred, P.soa, r, i);
    }
  }
  grid.sync();

  // ---- P6: pairwise mask, upper-triangle, grid-stride ----
  {
    const float* soa = P.soa;
    u64* mask = P.mask;
    int gw = gtid >> 6;
    int nwaves = NTHR >> 6;
    int WB = 1 << P.WBsh;
    int nUnits = (P.W/RPW) << P.WBsh;
    for (int u = gw; u < nUnits; u += nwaves){
      int rowg = u >> P.WBsh;
      int w = u & (WB - 1);
      if (((w + 1) << 6) <= rowg*RPW) continue;
      int j = (w << 6) + lane;
      float cx1 = soa[j], cy1 = soa[j + SOA_N], cx2 = soa[j + 2*SOA_N],
            cy2 = soa[j + 3*SOA_N], ca = soa[j + 4*SOA_N];
      #pragma unroll
      for (int rr = 0; rr < RPW; rr++){
        int i = rowg*RPW + rr;
        if (w < (i >> 6)) continue;
        float rx1 = soa[i], ry1 = soa[i + SOA_N], rx2 = soa[i + 2*SOA_N],
              ry2 = soa[i + 3*SOA_N], ra = soa[i + 4*SOA_N];
        float ltx = fmaxf(rx1, cx1), lty = fmaxf(ry1, cy1);
        float rbx = fminf(rx2, cx2), rby = fminf(ry2, cy2);
        float iw = fmaxf(rbx - ltx, 0.0f), ih = fmaxf(rby - lty, 0.0f);
        float inter = iw * ih;
        float iou = inter / ((ra + ca) - inter);
        u64 m = __ballot(iou > IOU_T);
        if (lane == 0) mask[(size_t)i*WB + w] = m;
      }
    }
  }
}

// ---- walk kernel: verbatim round-5-proven word-at-a-time LDS-diag walk ----
__global__ void __launch_bounds__(64) kwalk(const float* __restrict__ soa,
                                            const u64* __restrict__ mask,
                                            const u32* __restrict__ ctrl,
                                            float* __restrict__ out, int out_size,
                                            int W){
  __shared__ float kx1[320], ky1[320], kx2[320], ky2[320], ka[320];
  __shared__ u64 dlds[64];
  int lane = threadIdx.x;
  for (int o = lane; o < out_size; o += 64) out[o] = 0.0f;
  int numCand = (int)ctrl[C_NUM];
  int WB = W >> 6;
  int lim = numCand < W ? numCand : W;
  int nb = (lim + 63) >> 6;
  u64 rem0 = 0, rem1 = 0;
  int nsel = 0;

  u64 diag = 0;
  if (nb > 0 && lane < lim) diag = mask[(size_t)lane*WB + 0];

  for (int bi = 0; bi < nb && nsel < MAX_DET; bi++){
    u64 remw = (bi < 64) ? shfl64(rem0, bi) : shfl64(rem1, bi - 64);
    u64 w = ~remw;
    int rb = lim - (bi << 6);
    if (rb < 64) w &= ((1ull << rb) - 1ull);
    dlds[lane] = diag;
    __syncthreads();

    u64 diagn = 0;
    int inext = (bi + 1)*64 + lane;
    if (bi + 1 < nb && inext < lim) diagn = mask[(size_t)inext*WB + (bi + 1)];

    u64 sel = 0;
    int room = MAX_DET - nsel;
    while (w){
      int b = (int)__builtin_ctzll(w);
      sel |= (1ull << b);
      if (--room == 0) break;
      u64 rw = dlds[b];
      w &= ~rw;
      w &= ~(1ull << b);
    }
    int cnt = __popcll(sel);

    u64 s = sel;
    long long ids[8];
    #pragma unroll
    for (int q = 0; q < 8; q++){
      if (s){ ids[q] = (long long)((bi << 6) + __builtin_ctzll(s)); s &= s - 1; }
      else ids[q] = -1;
    }
    u64 a0[8], a1[8];
    #pragma unroll
    for (int q = 0; q < 8; q++){
      a0[q] = 0; a1[q] = 0;
      if (ids[q] >= 0){
        const u64* rp = mask + (size_t)ids[q]*WB;
        if (lane < WB)      a0[q] = rp[lane];
        if (64 + lane < WB) a1[q] = rp[64 + lane];
      }
    }

    if (lane < cnt){
      u64 t = sel;
      for (int q = 0; q < lane; q++) t &= t - 1;
      int b = (int)__builtin_ctzll(t);
      int i = (bi << 6) + b;
      int r = nsel + lane;
      kx1[r] = soa[i];            ky1[r] = soa[i + SOA_N];
      kx2[r] = soa[i + 2*SOA_N];  ky2[r] = soa[i + 3*SOA_N];
      ka[r]  = soa[i + 4*SOA_N];
      float* dr = out + r*6;
      dr[0] = soa[i + 7*SOA_N];  dr[1] = soa[i + 8*SOA_N];
      dr[2] = soa[i + 9*SOA_N];  dr[3] = soa[i + 10*SOA_N];
      dr[4] = soa[i + 5*SOA_N];  dr[5] = soa[i + 6*SOA_N];
      out[MAX_DET*6 + r] = 1.0f;
    }
    nsel += cnt;

    #pragma unroll
    for (int q = 0; q < 8; q++){ rem0 |= a0[q]; rem1 |= a1[q]; }

    while (s){
      long long ids2[8];
      #pragma unroll
      for (int q = 0; q < 8; q++){
        if (s){ ids2[q] = (long long)((bi << 6) + __builtin_ctzll(s)); s &= s - 1; }
        else ids2[q] = -1;
      }
      u64 b0[8], b1[8];
      #pragma unroll
      for (int q = 0; q < 8; q++){
        b0[q] = 0; b1[q] = 0;
        if (ids2[q] >= 0){
          const u64* rp = mask + (size_t)ids2[q]*WB;
          if (lane < WB)      b0[q] = rp[lane];
          if (64 + lane < WB) b1[q] = rp[64 + lane];
        }
      }
      #pragma unroll
      for (int q = 0; q < 8; q++){ rem0 |= b0[q]; rem1 |= b1[q]; }
    }
    diag = diagn;
    __syncthreads();
  }

  if (nsel < MAX_DET && numCand > W){
    for (int base = W; base < numCand && nsel < MAX_DET; base += 64){
      int li = base + lane;
      bool has = li < numCand;
      float cox1=0.f,coy1=0.f,cox2=0.f,coy2=0.f,car=1.f,csc=-1.f,ccl=0.f;
      float cbx1=0.f,cby1=0.f,cbx2=0.f,cby2=0.f;
      if (has){
        cox1 = soa[li]; coy1 = soa[li + SOA_N]; cox2 = soa[li + 2*SOA_N];
        coy2 = soa[li + 3*SOA_N]; car = soa[li + 4*SOA_N];
        csc = soa[li + 5*SOA_N]; ccl = soa[li + 6*SOA_N];
        cbx1 = soa[li + 7*SOA_N]; cby1 = soa[li + 8*SOA_N];
        cbx2 = soa[li + 9*SOA_N]; cby2 = soa[li + 10*SOA_N];
      }
      int m = min(64, numCand - base);
      for (int t2 = 0; t2 < m && nsel < MAX_DET; t2++){
        float qx1 = __shfl(cox1, t2), qy1 = __shfl(coy1, t2);
        float qx2 = __shfl(cox2, t2), qy2 = __shfl(coy2, t2);
        float qa  = __shfl(car,  t2);
        bool supp = false;
        #pragma unroll
        for (int q = 0; q < 5; q++){
          int slot = lane + (q << 6);
          if (slot < nsel){
            float ltx = fmaxf(qx1, kx1[slot]), lty = fmaxf(qy1, ky1[slot]);
            float rbx = fminf(qx2, kx2[slot]), rby = fminf(qy2, ky2[slot]);
            float iw = fmaxf(rbx - ltx, 0.0f), ih = fmaxf(rby - lty, 0.0f);
            float inter = iw * ih;
            float iou = inter / ((qa + ka[slot]) - inter);
            supp = supp || (iou > IOU_T);
          }
        }
        if (__any(supp)) continue;
        float bx1 = __shfl(cbx1, t2), by1 = __shfl(cby1, t2);
        float bx2 = __shfl(cbx2, t2), by2 = __shfl(cby2, t2);
        float sc  = __shfl(csc,  t2), cl  = __shfl(ccl,  t2);
        if (lane == 0){
          kx1[nsel] = qx1; ky1[nsel] = qy1; kx2[nsel] = qx2; ky2[nsel] = qy2; ka[nsel] = qa;
          float* dr = out + nsel*6;
          dr[0] = bx1; dr[1] = by1; dr[2] = bx2; dr[3] = by2; dr[4] = sc; dr[5] = cl;
          out[MAX_DET*6 + nsel] = 1.0f;
        }
        nsel++;
      }
    }
  }
}

extern "C" void kernel_launch(void* const* d_in, const int* in_sizes, int n_in,
                              void* d_out, int out_size, void* d_ws, size_t ws_size,
                              hipStream_t stream){
  const float* pred = (const float*)d_in[0];
  float* out = (float*)d_out;
  char* w = (char*)d_ws;

  KParams P;
  P.pred      = pred;
  P.keys      = (u32*)(w + 0x000000);   // 4 MB
  P.hist      = (u32*)(w + 0x400000);   // 256 KB
  P.binCursor = (u32*)(w + 0x440000);   // 256 KB
  P.ctrl      = (u32*)(w + 0x480000);   // 256 B
  P.chunkSum  = (u32*)(w + 0x484000);   // 4 KB
  P.binBase   = (u32*)(w + 0x4C0000);   // 256 KB
  P.eqKey     = (u32*)(w + 0x500000);   // 8 KB
  P.eqIdx     = (u32*)(w + 0x502000);   // 8 KB
  P.binnedKey = (u32*)(w + 0x510000);   // 120 KB
  P.binnedIdx = (u32*)(w + 0x530000);   // 120 KB
  P.soa       = (float*)(w + 0x550000); // 1.35 MB
  P.mask      = (u64*)(w + 0x6A0000);   // up to 8 MB

  if      (ws_size >= 0xEA0000){ P.W = 8192; P.WBsh = 7; }
  else if (ws_size >= 0x8A0000){ P.W = 4096; P.WBsh = 6; }
  else                         { P.W = 2048; P.WBsh = 5; }

  void* args[] = { (void*)&P };
  hipLaunchCooperativeKernel((const void*)kfused, dim3(GRID), dim3(256), args, 0, stream);
  kwalk<<<1, 64, 0, stream>>>(P.soa, P.mask, P.ctrl, out, out_size, P.W);
}

// Round 9
// 299.104 us; speedup vs baseline: 2.2467x; 2.2467x over previous
//
#include <hip/hip_runtime.h>
#include <stdint.h>

#pragma clang fp contract(off)

#define N_ELEM   1048576
#define MAX_NMS  30000
#define MAX_DET  300
#define IOU_T    0.45f
#define CONF_T   0.25f
#define SOA_N    30720
#define KMIN     0xBE800000u
#define EQCAP    2048

typedef uint32_t u32;
typedef unsigned long long u64;

// ctrl word indices
#define C_CB   0   // cutoff bin (0xFFFFFFFF if none)
#define C_KP   1   // entries to take from cutoff bin
#define C_A    2   // count of keys strictly above cutoff bin
#define C_NUM  3   // total candidates (min(total_valid, 30000))
#define C_EQC  4   // eq-list cursor (atomic)

__device__ inline u32 monokey(float s){
  u32 b = __float_as_uint(s);
  return b ^ ((b & 0x80000000u) ? 0xFFFFFFFFu : 0x80000000u);
}
__device__ inline int binOf(u32 k){
  u32 d = (k - KMIN) >> 8;
  return d > 65535u ? 65535 : (int)d;
}
__device__ inline u64 shfl64(u64 v, int src){
  int lo = __shfl((int)(u32)(v & 0xFFFFFFFFull), src);
  int hi = __shfl((int)(u32)(v >> 32), src);
  return ((u64)(u32)hi << 32) | (u32)lo;
}

// ---- kernel 1: LDS-staged keys (coalesced 28MB read) + 64K-bin histogram ----
__global__ void kkeys(const float4* __restrict__ pred4, u32* __restrict__ keys,
                      u32* __restrict__ hist){
  __shared__ float lds[1792];             // 256 rows x 7 floats
  int t = threadIdx.x;
  const float4* src = pred4 + (size_t)blockIdx.x * 448;
  float4* l4 = (float4*)lds;
  #pragma unroll
  for (int k = 0; k < 2; k++){
    int idx = k*256 + t;
    if (idx < 448) l4[idx] = src[idx];
  }
  __syncthreads();
  float obj = lds[t*7 + 4], c0 = lds[t*7 + 5], c1 = lds[t*7 + 6];
  float p0 = c0*obj, p1 = c1*obj;
  float conf = fmaxf(p0, p1);
  bool valid = (obj > CONF_T) && (conf > CONF_T);
  float score = valid ? conf : -1.0f;
  u32 mk = monokey(score);
  keys[blockIdx.x*256 + t] = mk;
  if (mk > KMIN) atomicAdd(&hist[binOf(mk)], 1u);
}

// ---- kernel 2: fused chunk-sum + cutoff-pick + binBase (one block, 16 waves) ----
__global__ void __launch_bounds__(1024) kselect(const u32* __restrict__ hist,
                                                u32* __restrict__ binBase,
                                                u32* __restrict__ ctrl){
  __shared__ u32 csum[1024];      // chunk sums, then chunkAbove
  __shared__ u32 s[1024];
  __shared__ int selC;
  __shared__ u32 chunk[64];
  int t = threadIdx.x, lane = t & 63, wv = t >> 6;   // 16 waves
  // phase 1: per-chunk sums, coalesced
  for (int j = 0; j < 64; j++){
    int c = wv*64 + j;
    u32 v = hist[c*64 + lane];
    #pragma unroll
    for (int off = 32; off > 0; off >>= 1) v += __shfl_down(v, off);
    if (lane == 0) csum[c] = v;
  }
  __syncthreads();
  // phase 2: suffix-scan of 1024 chunk sums + cutoff pick
  u32 own = csum[t];
  s[t] = own; __syncthreads();
  for (int off = 1; off < 1024; off <<= 1){
    u32 v = s[t];
    u32 add = (t + off < 1024) ? s[t + off] : 0u;
    __syncthreads();
    s[t] = v + add;
    __syncthreads();
  }
  u32 above = s[t] - own;
  u32 grand = s[0];
  csum[t] = above;                // now chunkAbove
  const u32 K = MAX_NMS;
  if (grand >= K && above < K && K <= above + own){ selC = t; }
  __syncthreads();
  if (grand >= K && t < 64) chunk[t] = hist[selC*64 + t];
  __syncthreads();
  if (t == 0){
    if (grand < K){
      ctrl[C_CB] = 0xFFFFFFFFu; ctrl[C_KP] = 0; ctrl[C_A] = grand; ctrl[C_NUM] = grand;
    } else {
      u32 cum = csum[selC];
      for (int b = 63; b >= 0; b--){
        u32 c = chunk[b];
        if (cum + c >= K){
          ctrl[C_CB] = (u32)(selC*64 + b);
          ctrl[C_KP] = K - cum;
          ctrl[C_A]  = cum;
          ctrl[C_NUM] = K;
          break;
        }
        cum += c;
      }
    }
  }
  // phase 3: binBase = count strictly above each bin
  for (int j = 0; j < 64; j++){
    int c = wv*64 + j;
    u32 v = hist[c*64 + lane];
    u32 suf = v;
    #pragma unroll
    for (int off = 1; off < 64; off <<= 1){
      u32 o = __shfl_down(suf, off);
      suf += (lane + off < 64) ? o : 0u;
    }
    binBase[c*64 + lane] = csum[c] + suf - v;
  }
}

// ---- kernel 3: scatter into per-bin slots; cutoff bin -> eq list ----
__global__ void kscatter(const uint4* __restrict__ keys4, const u32* __restrict__ binBase,
                         u32* __restrict__ binCursor, u32* __restrict__ ctrl,
                         u32* __restrict__ binnedKey, u32* __restrict__ binnedIdx,
                         u32* __restrict__ eqKey, u32* __restrict__ eqIdx){
  int t = blockIdx.x*blockDim.x + threadIdx.x;
  if (t >= N_ELEM/4) return;
  int cb = (int)ctrl[C_CB];
  uint4 kv = keys4[t];
  u32 kk[4] = {kv.x, kv.y, kv.z, kv.w};
  #pragma unroll
  for (int r = 0; r < 4; r++){
    u32 k = kk[r];
    if (k <= KMIN) continue;
    int b = binOf(k);
    u32 i = (u32)(t*4 + r);
    if (b > cb){
      u32 pos = binBase[b] + atomicAdd(&binCursor[b], 1u);
      if (pos < MAX_NMS){ binnedKey[pos] = k; binnedIdx[pos] = i; }
    } else if (b == cb){
      u32 e = atomicAdd(&ctrl[C_EQC], 1u);
      if (e < EQCAP){ eqKey[e] = k; eqIdx[e] = i; }
    }
  }
}

// ---- shared gather helper: write one SoA row ----
__device__ inline void writeSoA(const float* __restrict__ pred, float* __restrict__ soa,
                                u32 r, u32 i){
  const float* row = pred + (size_t)i*7;
  float x = row[0], y = row[1], w = row[2], hh = row[3];
  float obj = row[4], c0 = row[5], c1 = row[6];
  float p0 = c0*obj, p1 = c1*obj;
  float conf = fmaxf(p0, p1);
  float jf = (p0 >= p1) ? 0.0f : 1.0f;
  float bx1 = x - w*0.5f, by1 = y - hh*0.5f;
  float bx2 = x + w*0.5f, by2 = y + hh*0.5f;
  float off = jf * 4096.0f;
  float ox1 = bx1 + off, oy1 = by1 + off, ox2 = bx2 + off, oy2 = by2 + off;
  float area = (ox2 - ox1) * (oy2 - oy1);
  soa[r + 0*SOA_N] = ox1;  soa[r + 1*SOA_N] = oy1;
  soa[r + 2*SOA_N] = ox2;  soa[r + 3*SOA_N] = oy2;
  soa[r + 4*SOA_N] = area; soa[r + 5*SOA_N] = conf;
  soa[r + 6*SOA_N] = jf;
  soa[r + 7*SOA_N] = bx1;  soa[r + 8*SOA_N] = by1;
  soa[r + 9*SOA_N] = bx2;  soa[r +10*SOA_N] = by2;
}

// ---- kernel 4: exact rank within bin + eq-tie resolve + gather to SoA ----
__global__ void krank(const float* __restrict__ pred, const u32* __restrict__ binnedKey,
                      const u32* __restrict__ binnedIdx, const u32* __restrict__ binBase,
                      const u32* __restrict__ binHist, const u32* __restrict__ ctrl,
                      const u32* __restrict__ eqKey, const u32* __restrict__ eqIdx,
                      float* __restrict__ soa){
  int p = blockIdx.x*blockDim.x + threadIdx.x;
  u32 A = ctrl[C_A], Kp = ctrl[C_KP];
  // eq path: thread p handles eq entry p
  if (Kp > 0){
    u32 n = ctrl[C_EQC]; if (n > EQCAP) n = EQCAP;
    if (p < (int)n){
      u32 k = eqKey[p], i = eqIdx[p];
      u32 r = 0;
      for (u32 m = 0; m < n; m++){
        u32 km = eqKey[m], im = eqIdx[m];
        r += (km > k) || (km == k && im < i);
      }
      if (r < Kp) writeSoA(pred, soa, A + r, i);
    }
  }
  // normal path: binned entries occupy ranks [0, A)
  if (p < (int)A){
    u32 k = binnedKey[p]; u32 i = binnedIdx[p];
    if (i >= N_ELEM) i = 0;
    int b = binOf(k);
    u32 st = binBase[b], cnt = binHist[b];
    u32 r = st;
    for (u32 q = st; q < st + cnt; q++){
      u32 kq = binnedKey[q], iq = binnedIdx[q];
      if (kq > k || (kq == k && iq < i)) r++;
    }
    if (r < A) writeSoA(pred, soa, r, i);
  }
}

// ---- kernel 5: pairwise mask, line-owner stores ----
// unit = (16-row group, 8-word octet). One wave computes 16 rows x 512 cols;
// lane 0 writes each row's full 64B line -> no cross-wave/XCD false sharing.
__global__ void kmask(const float* __restrict__ soa, u64* __restrict__ mask,
                      int W, int WBsh, int nUnits){
  int lane = threadIdx.x & 63;
  int gw = (blockIdx.x*blockDim.x + threadIdx.x) >> 6;
  int nwaves = (gridDim.x*blockDim.x) >> 6;
  int WB = 1 << WBsh;
  int OCT = WB >> 3;                       // octets per row
  for (int u = gw; u < nUnits; u += nwaves){
    int rowg = u / OCT;
    int oct  = u - rowg*OCT;
    int base_row = rowg*16;
    // skip octets entirely below every row's diagonal word in this group
    if (((oct*8 + 8) << 6) <= base_row) continue;
    // register the 512 columns of this octet (5 floats x 8 chunks)
    float cX1[8], cY1[8], cX2[8], cY2[8], cA[8];
    int cbase = (oct << 9) + lane;
    #pragma unroll
    for (int cc = 0; cc < 8; cc++){
      int j = cbase + (cc << 6);
      cX1[cc] = soa[j];            cY1[cc] = soa[j + SOA_N];
      cX2[cc] = soa[j + 2*SOA_N];  cY2[cc] = soa[j + 3*SOA_N];
      cA[cc]  = soa[j + 4*SOA_N];
    }
    for (int rr = 0; rr < 16; rr++){
      int i = base_row + rr;
      float rx1 = soa[i], ry1 = soa[i + SOA_N], rx2 = soa[i + 2*SOA_N],
            ry2 = soa[i + 3*SOA_N], ra = soa[i + 4*SOA_N];
      u64 m0, m1, m2, m3, m4, m5, m6, m7;
      #pragma unroll
      for (int cc = 0; cc < 8; cc++){
        float ltx = fmaxf(rx1, cX1[cc]), lty = fmaxf(ry1, cY1[cc]);
        float rbx = fminf(rx2, cX2[cc]), rby = fminf(ry2, cY2[cc]);
        float iw = fmaxf(rbx - ltx, 0.0f), ih = fmaxf(rby - lty, 0.0f);
        float inter = iw * ih;
        float iou = inter / ((ra + cA[cc]) - inter);
        u64 m = __ballot(iou > IOU_T);
        switch (cc){
          case 0: m0 = m; break; case 1: m1 = m; break;
          case 2: m2 = m; break; case 3: m3 = m; break;
          case 4: m4 = m; break; case 5: m5 = m; break;
          case 6: m6 = m; break; case 7: m7 = m; break;
        }
      }
      if (lane == 0){
        u64* dst = mask + (size_t)i*WB + (oct << 3);
        dst[0] = m0; dst[1] = m1; dst[2] = m2; dst[3] = m3;
        dst[4] = m4; dst[5] = m5; dst[6] = m6; dst[7] = m7;
      }
    }
  }
}

// ---- kernel 6: word-at-a-time mask walk (LDS diag resolve) — round-5 proven ----
__global__ void __launch_bounds__(64) kwalk(const float* __restrict__ soa,
                                            const u64* __restrict__ mask,
                                            const u32* __restrict__ ctrl,
                                            float* __restrict__ out, int out_size,
                                            int W){
  __shared__ float kx1[320], ky1[320], kx2[320], ky2[320], ka[320];
  __shared__ u64 dlds[64];
  int lane = threadIdx.x;
  for (int o = lane; o < out_size; o += 64) out[o] = 0.0f;
  int numCand = (int)ctrl[C_NUM];
  int WB = W >> 6;
  int lim = numCand < W ? numCand : W;
  int nb = (lim + 63) >> 6;
  u64 rem0 = 0, rem1 = 0;
  int nsel = 0;

  u64 diag = 0;
  if (nb > 0 && lane < lim) diag = mask[(size_t)lane*WB + 0];

  for (int bi = 0; bi < nb && nsel < MAX_DET; bi++){
    u64 remw = (bi < 64) ? shfl64(rem0, bi) : shfl64(rem1, bi - 64);
    u64 w = ~remw;
    int rb = lim - (bi << 6);
    if (rb < 64) w &= ((1ull << rb) - 1ull);
    dlds[lane] = diag;
    __syncthreads();

    u64 diagn = 0;
    int inext = (bi + 1)*64 + lane;
    if (bi + 1 < nb && inext < lim) diagn = mask[(size_t)inext*WB + (bi + 1)];

    u64 sel = 0;
    int room = MAX_DET - nsel;
    while (w){
      int b = (int)__builtin_ctzll(w);
      sel |= (1ull << b);
      if (--room == 0) break;
      u64 rw = dlds[b];
      w &= ~rw;
      w &= ~(1ull << b);
    }
    int cnt = __popcll(sel);

    u64 s = sel;
    long long ids[8];
    #pragma unroll
    for (int q = 0; q < 8; q++){
      if (s){ ids[q] = (long long)((bi << 6) + __builtin_ctzll(s)); s &= s - 1; }
      else ids[q] = -1;
    }
    u64 a0[8], a1[8];
    #pragma unroll
    for (int q = 0; q < 8; q++){
      a0[q] = 0; a1[q] = 0;
      if (ids[q] >= 0){
        const u64* rp = mask + (size_t)ids[q]*WB;
        if (lane < WB)      a0[q] = rp[lane];
        if (64 + lane < WB) a1[q] = rp[64 + lane];
      }
    }

    if (lane < cnt){
      u64 t = sel;
      for (int q = 0; q < lane; q++) t &= t - 1;
      int b = (int)__builtin_ctzll(t);
      int i = (bi << 6) + b;
      int r = nsel + lane;
      kx1[r] = soa[i];            ky1[r] = soa[i + SOA_N];
      kx2[r] = soa[i + 2*SOA_N];  ky2[r] = soa[i + 3*SOA_N];
      ka[r]  = soa[i + 4*SOA_N];
      float* dr = out + r*6;
      dr[0] = soa[i + 7*SOA_N];  dr[1] = soa[i + 8*SOA_N];
      dr[2] = soa[i + 9*SOA_N];  dr[3] = soa[i + 10*SOA_N];
      dr[4] = soa[i + 5*SOA_N];  dr[5] = soa[i + 6*SOA_N];
      out[MAX_DET*6 + r] = 1.0f;
    }
    nsel += cnt;

    #pragma unroll
    for (int q = 0; q < 8; q++){ rem0 |= a0[q]; rem1 |= a1[q]; }

    while (s){
      long long ids2[8];
      #pragma unroll
      for (int q = 0; q < 8; q++){
        if (s){ ids2[q] = (long long)((bi << 6) + __builtin_ctzll(s)); s &= s - 1; }
        else ids2[q] = -1;
      }
      u64 b0[8], b1[8];
      #pragma unroll
      for (int q = 0; q < 8; q++){
        b0[q] = 0; b1[q] = 0;
        if (ids2[q] >= 0){
          const u64* rp = mask + (size_t)ids2[q]*WB;
          if (lane < WB)      b0[q] = rp[lane];
          if (64 + lane < WB) b1[q] = rp[64 + lane];
        }
      }
      #pragma unroll
      for (int q = 0; q < 8; q++){ rem0 |= b0[q]; rem1 |= b1[q]; }
    }
    diag = diagn;
    __syncthreads();
  }

  if (nsel < MAX_DET && numCand > W){
    for (int base = W; base < numCand && nsel < MAX_DET; base += 64){
      int li = base + lane;
      bool has = li < numCand;
      float cox1=0.f,coy1=0.f,cox2=0.f,coy2=0.f,car=1.f,csc=-1.f,ccl=0.f;
      float cbx1=0.f,cby1=0.f,cbx2=0.f,cby2=0.f;
      if (has){
        cox1 = soa[li]; coy1 = soa[li + SOA_N]; cox2 = soa[li + 2*SOA_N];
        coy2 = soa[li + 3*SOA_N]; car = soa[li + 4*SOA_N];
        csc = soa[li + 5*SOA_N]; ccl = soa[li + 6*SOA_N];
        cbx1 = soa[li + 7*SOA_N]; cby1 = soa[li + 8*SOA_N];
        cbx2 = soa[li + 9*SOA_N]; cby2 = soa[li + 10*SOA_N];
      }
      int m = min(64, numCand - base);
      for (int t2 = 0; t2 < m && nsel < MAX_DET; t2++){
        float qx1 = __shfl(cox1, t2), qy1 = __shfl(coy1, t2);
        float qx2 = __shfl(cox2, t2), qy2 = __shfl(coy2, t2);
        float qa  = __shfl(car,  t2);
        bool supp = false;
        #pragma unroll
        for (int q = 0; q < 5; q++){
          int slot = lane + (q << 6);
          if (slot < nsel){
            float ltx = fmaxf(qx1, kx1[slot]), lty = fmaxf(qy1, ky1[slot]);
            float rbx = fminf(qx2, kx2[slot]), rby = fminf(qy2, ky2[slot]);
            float iw = fmaxf(rbx - ltx, 0.0f), ih = fmaxf(rby - lty, 0.0f);
            float inter = iw * ih;
            float iou = inter / ((qa + ka[slot]) - inter);
            supp = supp || (iou > IOU_T);
          }
        }
        if (__any(supp)) continue;
        float bx1 = __shfl(cbx1, t2), by1 = __shfl(cby1, t2);
        float bx2 = __shfl(cbx2, t2), by2 = __shfl(cby2, t2);
        float sc  = __shfl(csc,  t2), cl  = __shfl(ccl,  t2);
        if (lane == 0){
          kx1[nsel] = qx1; ky1[nsel] = qy1; kx2[nsel] = qx2; ky2[nsel] = qy2; ka[nsel] = qa;
          float* dr = out + nsel*6;
          dr[0] = bx1; dr[1] = by1; dr[2] = bx2; dr[3] = by2; dr[4] = sc; dr[5] = cl;
          out[MAX_DET*6 + nsel] = 1.0f;
        }
        nsel++;
      }
    }
  }
}

extern "C" void kernel_launch(void* const* d_in, const int* in_sizes, int n_in,
                              void* d_out, int out_size, void* d_ws, size_t ws_size,
                              hipStream_t stream){
  const float* pred = (const float*)d_in[0];
  float* out = (float*)d_out;
  char* w = (char*)d_ws;

  u32*  keys       = (u32*)(w + 0x000000);   // 4 MB
  u32*  hist       = (u32*)(w + 0x400000);   // 256 KB
  u32*  binCursor  = (u32*)(w + 0x440000);   // 256 KB
  u32*  ctrl       = (u32*)(w + 0x480000);   // 256 B
  u32*  binBase    = (u32*)(w + 0x4C0000);   // 256 KB
  u32*  eqKey      = (u32*)(w + 0x500000);   // 8 KB
  u32*  eqIdx      = (u32*)(w + 0x502000);   // 8 KB
  u32*  binnedKey  = (u32*)(w + 0x510000);   // 120 KB
  u32*  binnedIdx  = (u32*)(w + 0x530000);   // 120 KB
  float* soa       = (float*)(w + 0x550000); // 1.35 MB
  u64*  mask       = (u64*)(w + 0x6A0000);   // up to 8 MB

  int W, WBsh;
  if      (ws_size >= 0xEA0000){ W = 8192; WBsh = 7; }
  else if (ws_size >= 0x8A0000){ W = 4096; WBsh = 6; }
  else                         { W = 2048; WBsh = 5; }

  hipMemsetAsync(hist, 0, 0x80100, stream);  // hist + binCursor + ctrl

  kkeys   <<<4096, 256, 0, stream>>>((const float4*)pred, keys, hist);
  kselect <<<1, 1024, 0, stream>>>(hist, binBase, ctrl);
  kscatter<<<1024, 256, 0, stream>>>((const uint4*)keys, binBase, binCursor, ctrl,
                                     binnedKey, binnedIdx, eqKey, eqIdx);
  krank   <<<(MAX_NMS + 255)/256 + 1, 256, 0, stream>>>(pred, binnedKey, binnedIdx, binBase,
                                                        hist, ctrl, eqKey, eqIdx, soa);
  int nUnits = (W >> 4) << (WBsh - 3);       // (W/16) * (WB/8)
  kmask   <<<2048, 256, 0, stream>>>(soa, mask, W, WBsh, nUnits);
  kwalk   <<<1, 64, 0, stream>>>(soa, mask, ctrl, out, out_size, W);
}